// Round 2
// baseline (886.694 us; speedup 1.0000x reference)
//
#include <hip/hip_runtime.h>
#include <hip/hip_bf16.h>
#include <stdint.h>

#define B_SZ  16
#define S_SZ  2048
#define D_SZ  1024
#define FF_SZ 4096
#define DT_SZ 512

typedef __bf16 bf16x8 __attribute__((ext_vector_type(8)));
typedef float  f32x4  __attribute__((ext_vector_type(4)));
typedef short  short8 __attribute__((ext_vector_type(8)));

__device__ __forceinline__ short f2bf(float x) {
    union { float f; uint32_t u; } v; v.f = x;
    uint32_t r = (v.u + 0x7fffu + ((v.u >> 16) & 1u)) >> 16;  // RNE
    return (short)(uint16_t)r;
}

// ---------------- cast f32 -> bf16, 8 elems/thread ----------------
__global__ void cast_x_kernel(const float* __restrict__ src, short* __restrict__ dst, int n8) {
    int i = blockIdx.x * 256 + threadIdx.x;
    if (i >= n8) return;
    const float4* s4 = reinterpret_cast<const float4*>(src);
    float4 a = s4[2 * i], b = s4[2 * i + 1];
    short8 v;
    v[0] = f2bf(a.x); v[1] = f2bf(a.y); v[2] = f2bf(a.z); v[3] = f2bf(a.w);
    v[4] = f2bf(b.x); v[5] = f2bf(b.y); v[6] = f2bf(b.z); v[7] = f2bf(b.w);
    reinterpret_cast<short8*>(dst)[i] = v;
}

// ---------------- transpose + cast: src f32 [R][C] -> dst bf16 [C][R] ----------------
__global__ void transpose_cast_kernel(const float* __restrict__ src, short* __restrict__ dst,
                                      int R, int C) {
    __shared__ float tile[32][33];
    int c0 = blockIdx.x * 32, r0 = blockIdx.y * 32;
    int tx = threadIdx.x, ty = threadIdx.y;   // 32 x 8
#pragma unroll
    for (int i = 0; i < 32; i += 8)
        tile[ty + i][tx] = src[(size_t)(r0 + ty + i) * C + (c0 + tx)];
    __syncthreads();
#pragma unroll
    for (int i = 0; i < 32; i += 8)
        dst[(size_t)(c0 + ty + i) * R + (r0 + tx)] = f2bf(tile[tx][ty + i]);
}

// =====================================================================
// 256x256-tile bf16 GEMM: C = A(MxK) * Bt(NxK)^T
// 8 waves (2M x 4N), BK=32, 4-deep LDS ring (128 KiB), counted vmcnt,
// XOR-swizzled LDS (conflict-free ds_read_b128), setprio around MFMA.
// =====================================================================

// stage one K-tile (A: 256x32 bf16 = 16KB, B same) = 4 global_load_lds x16B
#define STAGE(slotp, kofs) do {                                                              \
    const int s_ = (slotp);                                                                  \
    __builtin_amdgcn_global_load_lds(                                                        \
        (__attribute__((address_space(1))) void*)(pA0 + (kofs)),                             \
        (__attribute__((address_space(3))) void*)&As[s_][w * 512], 16, 0, 0);                \
    __builtin_amdgcn_global_load_lds(                                                        \
        (__attribute__((address_space(1))) void*)(pA1 + (kofs)),                             \
        (__attribute__((address_space(3))) void*)&As[s_][4096 + w * 512], 16, 0, 0);         \
    __builtin_amdgcn_global_load_lds(                                                        \
        (__attribute__((address_space(1))) void*)(pB0 + (kofs)),                             \
        (__attribute__((address_space(3))) void*)&Bs[s_][w * 512], 16, 0, 0);                \
    __builtin_amdgcn_global_load_lds(                                                        \
        (__attribute__((address_space(1))) void*)(pB1 + (kofs)),                             \
        (__attribute__((address_space(3))) void*)&Bs[s_][4096 + w * 512], 16, 0, 0);         \
} while (0)

// consume one K-tile: 12 swizzled ds_read_b128 + 32 MFMA, barrier-fenced
#define KTILE(slotp) do {                                                                    \
    const int s_ = (slotp);                                                                  \
    __builtin_amdgcn_s_barrier();                                                            \
    asm volatile("" ::: "memory");                                                           \
    __builtin_amdgcn_sched_barrier(0);                                                       \
    bf16x8 af[8]; bf16x8 bfr[4];                                                             \
    _Pragma("unroll")                                                                        \
    for (int mi = 0; mi < 8; ++mi) {                                                         \
        const int r_ = wm * 128 + mi * 16 + l15;                                             \
        const int ix = ((r_ * 64 + kq * 16) ^ (((r_ >> 1) & 7) << 4)) >> 1;                  \
        af[mi] = *reinterpret_cast<const bf16x8*>(&As[s_][ix]);                              \
    }                                                                                        \
    _Pragma("unroll")                                                                        \
    for (int ni = 0; ni < 4; ++ni) {                                                         \
        const int r_ = wn * 64 + ni * 16 + l15;                                              \
        const int ix = ((r_ * 64 + kq * 16) ^ (((r_ >> 1) & 7) << 4)) >> 1;                  \
        bfr[ni] = *reinterpret_cast<const bf16x8*>(&Bs[s_][ix]);                             \
    }                                                                                        \
    __builtin_amdgcn_s_setprio(1);                                                           \
    _Pragma("unroll")                                                                        \
    for (int mi = 0; mi < 8; ++mi)                                                           \
        _Pragma("unroll")                                                                    \
        for (int ni = 0; ni < 4; ++ni)                                                       \
            acc[mi][ni] = __builtin_amdgcn_mfma_f32_16x16x32_bf16(af[mi], bfr[ni],           \
                                                                  acc[mi][ni], 0, 0, 0);     \
    __builtin_amdgcn_s_setprio(0);                                                           \
    asm volatile("" ::: "memory");                                                           \
    __builtin_amdgcn_sched_barrier(0);                                                       \
    __builtin_amdgcn_s_barrier();                                                            \
} while (0)

template <bool GELU_BF16>
__global__ __launch_bounds__(512, 2)
void gemm256_kernel(const short* __restrict__ A, const short* __restrict__ Bt,
                    void* __restrict__ Cout, int M, int N, int K) {
    __shared__ short As[4][8192];   // 4-ring, A tile 256 rows x 32 k (64B rows)
    __shared__ short Bs[4][8192];

    const int tid = threadIdx.x;
    const int w   = tid >> 6;
    const int l   = tid & 63;
    const int wm  = w >> 2;        // 0..1
    const int wn  = w & 3;         // 0..3
    const int kq  = l >> 4;        // 0..3
    const int l15 = l & 15;

    // XCD-bijective block swizzle (grids are multiples of 8 by construction)
    const int nwg = gridDim.x;
    int swzw = blockIdx.x;
    if ((nwg & 7) == 0) swzw = (swzw & 7) * (nwg >> 3) + (swzw >> 3);
    const int MB = M >> 8;
    const int bm = swzw % MB, bn = swzw / MB;
    const int m0 = bm << 8, n0 = bn << 8;

    // staging: linear LDS dest (HW: wave-uniform base + lane*16), inverse-swizzled
    // global source. Physical byte X in 16KB tile -> logical P = X ^ ((X>>7 & 7)<<4),
    // row = P>>6 (64B logical rows), col elems = (P&63)>>1.
    const short *pA0, *pA1, *pB0, *pB1;
    {
        int X0 = tid * 16;
        int P0 = X0 ^ (((X0 >> 7) & 7) << 4);
        int r0_ = P0 >> 6, c0_ = (P0 & 63) >> 1;
        int X1 = 8192 + tid * 16;
        int P1 = X1 ^ (((X1 >> 7) & 7) << 4);
        int r1_ = P1 >> 6, c1_ = (P1 & 63) >> 1;
        pA0 = A  + (size_t)(m0 + r0_) * K + c0_;
        pA1 = A  + (size_t)(m0 + r1_) * K + c1_;
        pB0 = Bt + (size_t)(n0 + r0_) * K + c0_;
        pB1 = Bt + (size_t)(n0 + r1_) * K + c1_;
    }

    f32x4 acc[8][4];
#pragma unroll
    for (int mi = 0; mi < 8; ++mi)
#pragma unroll
        for (int ni = 0; ni < 4; ++ni)
            acc[mi][ni] = (f32x4){0.f, 0.f, 0.f, 0.f};

    const int NT = K >> 5;   // K-tiles of 32; NT >= 4 for all our shapes

    // prologue: tiles 0,1,2 in flight (12 loads)
    STAGE(0, 0);
    STAGE(1, 32);
    STAGE(2, 64);

    int t = 0;
    for (; t + 3 < NT; ++t) {
        const int nt_ = t + 3;
        STAGE(nt_ & 3, nt_ << 5);                       // 16 outstanding
        asm volatile("s_waitcnt vmcnt(12)" ::: "memory"); // oldest 4 (tile t) done
        KTILE(t & 3);
    }
    asm volatile("s_waitcnt vmcnt(8)" ::: "memory");
    KTILE(t & 3); ++t;
    asm volatile("s_waitcnt vmcnt(4)" ::: "memory");
    KTILE(t & 3); ++t;
    asm volatile("s_waitcnt vmcnt(0)" ::: "memory");
    KTILE(t & 3);

    // epilogue — D layout (m89): col = lane&15, row = (lane>>4)*4 + reg
    const int row_base = m0 + wm * 128 + kq * 4;
    const int col_base = n0 + wn * 64 + l15;
    if constexpr (GELU_BF16) {
        short* C = reinterpret_cast<short*>(Cout);
#pragma unroll
        for (int mi = 0; mi < 8; ++mi)
#pragma unroll
            for (int r = 0; r < 4; ++r) {
                const size_t ro = (size_t)(row_base + mi * 16 + r) * N;
#pragma unroll
                for (int ni = 0; ni < 4; ++ni) {
                    float x = acc[mi][ni][r];
                    float u = 0.7978845608028654f * (x + 0.044715f * x * x * x);
                    float g = x / (1.f + __expf(-2.f * u));
                    C[ro + col_base + ni * 16] = f2bf(g);
                }
            }
    } else {
        float* C = reinterpret_cast<float*>(Cout);
#pragma unroll
        for (int mi = 0; mi < 8; ++mi)
#pragma unroll
            for (int r = 0; r < 4; ++r) {
                const size_t ro = (size_t)(row_base + mi * 16 + r) * N;
#pragma unroll
                for (int ni = 0; ni < 4; ++ni)
                    C[ro + col_base + ni * 16] = acc[mi][ni][r];
            }
    }
}

// ---------------- intervention: out[b, eot[b], 0:512] = row[0:512] @ Wrot @ Winv ----------------
__global__ void intervention_kernel(const float* __restrict__ Wrot, const float* __restrict__ Winv,
                                    const int* __restrict__ eot, float* __restrict__ out) {
    __shared__ float tgt[DT_SZ];
    __shared__ float tmp[DT_SZ];
    const int b = blockIdx.x;
    const int j = threadIdx.x;
    float* row = out + ((size_t)b * S_SZ + eot[b]) * D_SZ;
    tgt[j] = row[j];                      // ST=0 slice
    __syncthreads();
    float s = 0.f;
#pragma unroll 8
    for (int i = 0; i < DT_SZ; ++i) s = fmaf(tgt[i], Wrot[(size_t)i * DT_SZ + j], s);
    tmp[j] = s;
    __syncthreads();
    float s2 = 0.f;
#pragma unroll 8
    for (int i = 0; i < DT_SZ; ++i) s2 = fmaf(tmp[i], Winv[(size_t)i * DT_SZ + j], s2);
    row[j] = s2;
}

extern "C" void kernel_launch(void* const* d_in, const int* in_sizes, int n_in,
                              void* d_out, int out_size, void* d_ws, size_t ws_size,
                              hipStream_t stream) {
    const float* hidden = (const float*)d_in[0];
    const float* W1     = (const float*)d_in[1];
    const float* W2     = (const float*)d_in[2];
    const float* Wrot   = (const float*)d_in[3];
    const float* Winv   = (const float*)d_in[4];
    const int*   eot    = (const int*)d_in[5];
    float* out = (float*)d_out;

    const int M = B_SZ * S_SZ;   // 32768

    // ws layout: W1t (FF x D bf16) | W2t (D x FF bf16) | Xbf chunk | C1 chunk
    short* W1t = (short*)d_ws;
    short* W2t = W1t + (size_t)FF_SZ * D_SZ;
    short* Xbf = W2t + (size_t)FF_SZ * D_SZ;
    const size_t fixed_bytes = 2ull * (size_t)FF_SZ * D_SZ * sizeof(short);  // 16 MiB
    const size_t per_row = (size_t)D_SZ * 2 + (size_t)FF_SZ * 2;             // 10240 B
    size_t rem = ws_size > fixed_bytes ? ws_size - fixed_bytes : 0;
    int Mc = (int)(rem / per_row);
    Mc = (Mc / 512) * 512;       // 512-alignment keeps every grid a multiple of 8
    if (Mc < 512) Mc = 512;
    if (Mc > M) Mc = M;
    short* C1 = Xbf + (size_t)Mc * D_SZ;

    transpose_cast_kernel<<<dim3(FF_SZ / 32, D_SZ / 32), dim3(32, 8), 0, stream>>>(W1, W1t, D_SZ, FF_SZ);
    transpose_cast_kernel<<<dim3(D_SZ / 32, FF_SZ / 32), dim3(32, 8), 0, stream>>>(W2, W2t, FF_SZ, D_SZ);

    for (int ms = 0; ms < M; ms += Mc) {
        const int mc = (M - ms < Mc) ? (M - ms) : Mc;   // multiple of 512
        const int n8 = mc * D_SZ / 8;
        cast_x_kernel<<<(n8 + 255) / 256, 256, 0, stream>>>(hidden + (size_t)ms * D_SZ, Xbf, n8);
        gemm256_kernel<true ><<<dim3((mc / 256) * (FF_SZ / 256)), 512, 0, stream>>>(
            Xbf, W1t, C1, mc, FF_SZ, D_SZ);
        gemm256_kernel<false><<<dim3((mc / 256) * (D_SZ / 256)), 512, 0, stream>>>(
            C1, W2t, out + (size_t)ms * D_SZ, mc, D_SZ, FF_SZ);
    }
    intervention_kernel<<<B_SZ, DT_SZ, 0, stream>>>(Wrot, Winv, eot, out);
}

// Round 4
// 717.690 us; speedup vs baseline: 1.2355x; 1.2355x over previous
//
#include <hip/hip_runtime.h>
#include <hip/hip_bf16.h>
#include <stdint.h>

#define B_SZ  16
#define S_SZ  2048
#define D_SZ  1024
#define FF_SZ 4096
#define DT_SZ 512

typedef __bf16 bf16x8 __attribute__((ext_vector_type(8)));
typedef float  f32x4  __attribute__((ext_vector_type(4)));
typedef short  short8 __attribute__((ext_vector_type(8)));

__device__ __forceinline__ short f2bf(float x) {
    union { float f; uint32_t u; } v; v.f = x;
    uint32_t r = (v.u + 0x7fffu + ((v.u >> 16) & 1u)) >> 16;  // RNE
    return (short)(uint16_t)r;
}

// ---------------- cast f32 -> bf16, 8 elems/thread ----------------
__global__ void cast_x_kernel(const float* __restrict__ src, short* __restrict__ dst, int n8) {
    int i = blockIdx.x * 256 + threadIdx.x;
    if (i >= n8) return;
    const float4* s4 = reinterpret_cast<const float4*>(src);
    float4 a = s4[2 * i], b = s4[2 * i + 1];
    short8 v;
    v[0] = f2bf(a.x); v[1] = f2bf(a.y); v[2] = f2bf(a.z); v[3] = f2bf(a.w);
    v[4] = f2bf(b.x); v[5] = f2bf(b.y); v[6] = f2bf(b.z); v[7] = f2bf(b.w);
    reinterpret_cast<short8*>(dst)[i] = v;
}

// ---------------- transpose + cast: src f32 [R][C] -> dst bf16 [C][R] ----------------
__global__ void transpose_cast_kernel(const float* __restrict__ src, short* __restrict__ dst,
                                      int R, int C) {
    __shared__ float tile[32][33];
    int c0 = blockIdx.x * 32, r0 = blockIdx.y * 32;
    int tx = threadIdx.x, ty = threadIdx.y;   // 32 x 8
#pragma unroll
    for (int i = 0; i < 32; i += 8)
        tile[ty + i][tx] = src[(size_t)(r0 + ty + i) * C + (c0 + tx)];
    __syncthreads();
#pragma unroll
    for (int i = 0; i < 32; i += 8)
        dst[(size_t)(c0 + ty + i) * R + (r0 + tx)] = f2bf(tile[tx][ty + i]);
}

// =====================================================================
// 256x256-tile bf16 GEMM: C = A(MxK) * Bt(NxK)^T
// 8 waves (2M x 4N), BK=32, 4-slot LDS ring, ONE barrier per K-tile:
//   vmcnt(NW) ; s_barrier ; 12 ds_read_b128 ; 4 global_load_lds ; 32 MFMA
// Counted vmcnt (12 loads in flight steady-state, never 0), XOR-swizzled
// LDS (0 bank conflicts), hoisted offsets, setprio around MFMA cluster.
// =====================================================================

#define GLOAD(srcp, dstofs)                                                   \
    __builtin_amdgcn_global_load_lds(                                         \
        (__attribute__((address_space(1))) void*)(srcp),                      \
        (__attribute__((address_space(3))) void*)(ldsb + (dstofs)), 16, 0, 0)

#define WSLOT(S) (((S) + 3) & 3)

// One K-tile: slot S (literal 0..3), entry wait NW (literal), STG literal bool,
// TT = tile index being computed (stages tile TT+3 when STG).
#define TILE(S, NW, STG, TT) do {                                                           \
    asm volatile("s_waitcnt vmcnt(" #NW ")" ::: "memory");                                  \
    __builtin_amdgcn_s_barrier();                                                           \
    asm volatile("" ::: "memory");                                                          \
    __builtin_amdgcn_sched_barrier(0);                                                      \
    bf16x8 af0[4], af1[4], bfv[4];                                                          \
    _Pragma("unroll")                                                                       \
    for (int ni = 0; ni < 4; ++ni)                                                          \
        bfv[ni] = *reinterpret_cast<const bf16x8*>(ldsb + (S) * 32768 + offB[ni]);          \
    _Pragma("unroll")                                                                       \
    for (int mi = 0; mi < 4; ++mi)                                                          \
        af0[mi] = *reinterpret_cast<const bf16x8*>(ldsb + (S) * 32768 + offA[mi]);          \
    _Pragma("unroll")                                                                       \
    for (int mi = 0; mi < 4; ++mi)                                                          \
        af1[mi] = *reinterpret_cast<const bf16x8*>(ldsb + (S) * 32768 + offA[4 + mi]);      \
    if (STG) {                                                                              \
        GLOAD(gA0 + (size_t)(TT + 3) * 32, WSLOT(S) * 32768 +         w * 1024);            \
        GLOAD(gA1 + (size_t)(TT + 3) * 32, WSLOT(S) * 32768 +  8192 + w * 1024);            \
        GLOAD(gB0 + (size_t)(TT + 3) * 32, WSLOT(S) * 32768 + 16384 + w * 1024);            \
        GLOAD(gB1 + (size_t)(TT + 3) * 32, WSLOT(S) * 32768 + 24576 + w * 1024);            \
    }                                                                                       \
    __builtin_amdgcn_s_setprio(1);                                                          \
    _Pragma("unroll")                                                                       \
    for (int mi = 0; mi < 4; ++mi)                                                          \
        _Pragma("unroll")                                                                   \
        for (int ni = 0; ni < 4; ++ni)                                                      \
            acc[mi][ni] = __builtin_amdgcn_mfma_f32_16x16x32_bf16(af0[mi], bfv[ni],         \
                                                                  acc[mi][ni], 0, 0, 0);    \
    _Pragma("unroll")                                                                       \
    for (int mi = 0; mi < 4; ++mi)                                                          \
        _Pragma("unroll")                                                                   \
        for (int ni = 0; ni < 4; ++ni)                                                      \
            acc[4 + mi][ni] = __builtin_amdgcn_mfma_f32_16x16x32_bf16(af1[mi], bfv[ni],     \
                                                                  acc[4 + mi][ni], 0, 0, 0);\
    __builtin_amdgcn_s_setprio(0);                                                          \
} while (0)

template <bool GELU_BF16>
__global__ __launch_bounds__(512, 2)
void gemm256_kernel(const short* __restrict__ A, const short* __restrict__ Bt,
                    void* __restrict__ Cout, int M, int N, int K) {
    __shared__ char lds4[4][32768];   // slot: A tile [256][32]bf16 @0, B tile @16384
    char* ldsb = &lds4[0][0];

    const int tid = threadIdx.x;
    const int w   = tid >> 6;
    const int l   = tid & 63;
    const int wm  = w >> 2;        // 0..1
    const int wn  = w & 3;         // 0..3
    const int kq  = l >> 4;        // 0..3
    const int l15 = l & 15;

    // XCD-bijective block swizzle (grids are multiples of 8 by construction)
    const int nwg = gridDim.x;
    int swzw = blockIdx.x;
    if ((nwg & 7) == 0) swzw = (swzw & 7) * (nwg >> 3) + (swzw >> 3);
    const int MB = M >> 8;
    const int bm = swzw % MB, bn = swzw / MB;
    const int m0 = bm << 8, n0 = bn << 8;

    // ---- loop-invariant swizzled ds_read byte offsets (registers) ----
    // logical byte = row*64 + kq*16 ; phys = logical ^ (((row>>1)&7)<<4)
    int offA[8], offB[4];
#pragma unroll
    for (int mi = 0; mi < 8; ++mi) {
        const int r = wm * 128 + mi * 16 + l15;
        offA[mi] = (r * 64 + kq * 16) ^ (((r >> 1) & 7) << 4);
    }
#pragma unroll
    for (int ni = 0; ni < 4; ++ni) {
        const int r = wn * 64 + ni * 16 + l15;
        offB[ni] = 16384 + ((r * 64 + kq * 16) ^ (((r >> 1) & 7) << 4));
    }

    // ---- staging source addresses (inverse-swizzled global, linear LDS dest) ----
    // per 8KB chunk: thread writes LDS byte X=tid*16; logical P = X ^ (((X>>7)&7)<<4)
    const int X  = tid * 16;
    const int P  = X ^ (((X >> 7) & 7) << 4);
    const int rS = P >> 6;            // 0..127 (64B rows)
    const int cS = (P & 63) >> 1;     // element col, multiple of 8
    const short* gA0 = A  + (size_t)(m0 + rS) * K + cS;
    const short* gA1 = gA0 + (size_t)128 * K;
    const short* gB0 = Bt + (size_t)(n0 + rS) * K + cS;
    const short* gB1 = gB0 + (size_t)128 * K;

    f32x4 acc[8][4];
#pragma unroll
    for (int mi = 0; mi < 8; ++mi)
#pragma unroll
        for (int ni = 0; ni < 4; ++ni)
            acc[mi][ni] = (f32x4){0.f, 0.f, 0.f, 0.f};

    const int NT = K >> 5;            // K-tiles of 32 (multiple of 4 for our shapes)

    // prologue: tiles 0,1,2 in flight (12 loads; order A0,A1,B0,B1 per tile)
#pragma unroll
    for (int x = 0; x < 3; ++x) {
        GLOAD(gA0 + x * 32, x * 32768 +         w * 1024);
        GLOAD(gA1 + x * 32, x * 32768 +  8192 + w * 1024);
        GLOAD(gB0 + x * 32, x * 32768 + 16384 + w * 1024);
        GLOAD(gB1 + x * 32, x * 32768 + 24576 + w * 1024);
    }

    int t = 0;
    for (; t + 8 <= NT; t += 4) {     // steady state: always 12 loads in flight
        TILE(0, 8, true, t);
        TILE(1, 8, true, t + 1);
        TILE(2, 8, true, t + 2);
        TILE(3, 8, true, t + 3);
    }
    // final group (t == NT-4): stage last tile, then drain 8 -> 4 -> 0
    TILE(0, 8, true,  t);
    TILE(1, 8, false, t + 1);
    TILE(2, 4, false, t + 2);
    TILE(3, 0, false, t + 3);

    // epilogue — D layout (m89): col = lane&15, row = (lane>>4)*4 + reg
    const int row_base = m0 + wm * 128 + kq * 4;
    const int col_base = n0 + wn * 64 + l15;
    if constexpr (GELU_BF16) {
        short* C = reinterpret_cast<short*>(Cout);
#pragma unroll
        for (int mi = 0; mi < 8; ++mi)
#pragma unroll
            for (int r = 0; r < 4; ++r) {
                const size_t ro = (size_t)(row_base + mi * 16 + r) * N;
#pragma unroll
                for (int ni = 0; ni < 4; ++ni) {
                    float x = acc[mi][ni][r];
                    float u = 0.7978845608028654f * (x + 0.044715f * x * x * x);
                    float g = x / (1.f + __expf(-2.f * u));
                    C[ro + col_base + ni * 16] = f2bf(g);
                }
            }
    } else {
        float* C = reinterpret_cast<float*>(Cout);
#pragma unroll
        for (int mi = 0; mi < 8; ++mi)
#pragma unroll
            for (int r = 0; r < 4; ++r) {
                const size_t ro = (size_t)(row_base + mi * 16 + r) * N;
#pragma unroll
                for (int ni = 0; ni < 4; ++ni)
                    C[ro + col_base + ni * 16] = acc[mi][ni][r];
            }
    }
}

// ---------------- intervention: out[b, eot[b], 0:512] = row[0:512] @ Wrot @ Winv ----------------
__global__ void intervention_kernel(const float* __restrict__ Wrot, const float* __restrict__ Winv,
                                    const int* __restrict__ eot, float* __restrict__ out) {
    __shared__ float tgt[DT_SZ];
    __shared__ float tmp[DT_SZ];
    const int b = blockIdx.x;
    const int j = threadIdx.x;
    float* row = out + ((size_t)b * S_SZ + eot[b]) * D_SZ;
    tgt[j] = row[j];                      // ST=0 slice
    __syncthreads();
    float s = 0.f;
#pragma unroll 8
    for (int i = 0; i < DT_SZ; ++i) s = fmaf(tgt[i], Wrot[(size_t)i * DT_SZ + j], s);
    tmp[j] = s;
    __syncthreads();
    float s2 = 0.f;
#pragma unroll 8
    for (int i = 0; i < DT_SZ; ++i) s2 = fmaf(tmp[i], Winv[(size_t)i * DT_SZ + j], s2);
    row[j] = s2;
}

extern "C" void kernel_launch(void* const* d_in, const int* in_sizes, int n_in,
                              void* d_out, int out_size, void* d_ws, size_t ws_size,
                              hipStream_t stream) {
    const float* hidden = (const float*)d_in[0];
    const float* W1     = (const float*)d_in[1];
    const float* W2     = (const float*)d_in[2];
    const float* Wrot   = (const float*)d_in[3];
    const float* Winv   = (const float*)d_in[4];
    const int*   eot    = (const int*)d_in[5];
    float* out = (float*)d_out;

    const int M = B_SZ * S_SZ;   // 32768

    // ws layout: W1t (FF x D bf16) | W2t (D x FF bf16) | Xbf chunk | C1 chunk
    short* W1t = (short*)d_ws;
    short* W2t = W1t + (size_t)FF_SZ * D_SZ;
    short* Xbf = W2t + (size_t)FF_SZ * D_SZ;
    const size_t fixed_bytes = 2ull * (size_t)FF_SZ * D_SZ * sizeof(short);  // 16 MiB
    const size_t per_row = (size_t)D_SZ * 2 + (size_t)FF_SZ * 2;             // 10240 B
    size_t rem = ws_size > fixed_bytes ? ws_size - fixed_bytes : 0;
    int Mc = (int)(rem / per_row);
    Mc = (Mc / 512) * 512;       // keeps every grid a multiple of 8
    if (Mc < 512) Mc = 512;
    if (Mc > M) Mc = M;
    short* C1 = Xbf + (size_t)Mc * D_SZ;

    transpose_cast_kernel<<<dim3(FF_SZ / 32, D_SZ / 32), dim3(32, 8), 0, stream>>>(W1, W1t, D_SZ, FF_SZ);
    transpose_cast_kernel<<<dim3(D_SZ / 32, FF_SZ / 32), dim3(32, 8), 0, stream>>>(W2, W2t, FF_SZ, D_SZ);

    for (int ms = 0; ms < M; ms += Mc) {
        const int mc = (M - ms < Mc) ? (M - ms) : Mc;   // multiple of 512
        const int n8 = mc * D_SZ / 8;
        cast_x_kernel<<<(n8 + 255) / 256, 256, 0, stream>>>(hidden + (size_t)ms * D_SZ, Xbf, n8);
        gemm256_kernel<true ><<<dim3((mc / 256) * (FF_SZ / 256)), 512, 0, stream>>>(
            Xbf, W1t, C1, mc, FF_SZ, D_SZ);
        gemm256_kernel<false><<<dim3((mc / 256) * (D_SZ / 256)), 512, 0, stream>>>(
            C1, W2t, out + (size_t)ms * D_SZ, mc, D_SZ, FF_SZ);
    }
    intervention_kernel<<<B_SZ, DT_SZ, 0, stream>>>(Wrot, Winv, eot, out);
}